// Round 3
// baseline (6667.262 us; speedup 1.0000x reference)
//
#include <hip/hip_runtime.h>
#include <stdint.h>

#define N_NODES 50000
#define HIDDEN  512
#define N_EDGES 200000

#define TM 64
#define TN 64
#define BK 32
#define LDP 40   // padded LDS row stride in bf16 elems (80B: 16B-aligned, 2-way bank alias only)

typedef __attribute__((ext_vector_type(8))) short   short8;
typedef __attribute__((ext_vector_type(4))) float   floatx4;

__device__ inline float bf2f(ushort u) {
    union { uint32_t u; float f; } v; v.u = ((uint32_t)u) << 16; return v.f;
}
__device__ inline ushort f2bf(float f) {
    union { float f; uint32_t u; } v; v.f = f;
    uint32_t r = v.u + 0x7fffu + ((v.u >> 16) & 1u);   // round-to-nearest-even
    return (ushort)(r >> 16);
}
__device__ inline floatx4 mfma16(short8 a, short8 b, floatx4 c) {
    return __builtin_amdgcn_mfma_f32_16x16x32_bf16(a, b, c, 0, 0, 0);
}
// inputs is arange(N_NODES); if harness kept int64, the int32 view is [0,0,1,0,2,0,...]
__device__ inline bool idx_is64(const int* __restrict__ inputs) {
    return inputs[1] == 0 && inputs[2] == 1;
}

// x = bf16(emb[inputs]) : 8 f32 -> 8 bf16 per thread
__global__ void k_gather(const int* __restrict__ inputs, const float* __restrict__ emb,
                         ushort* __restrict__ xb) {
    bool is64 = idx_is64(inputs);
    int t = blockIdx.x * blockDim.x + threadIdx.x;   // N_NODES*64 threads
    int row = t >> 6, s8 = (t & 63) << 3;
    if (row >= N_NODES) return;
    int srow = is64 ? inputs[2 * row] : inputs[row];
    srow = srow < 0 ? 0 : (srow >= N_NODES ? N_NODES - 1 : srow);
    const float* src = emb + (size_t)srow * HIDDEN + s8;
    float4 v0 = *(const float4*)(src);
    float4 v1 = *(const float4*)(src + 4);
    ushort o[8] = { f2bf(v0.x), f2bf(v0.y), f2bf(v0.z), f2bf(v0.w),
                    f2bf(v1.x), f2bf(v1.y), f2bf(v1.z), f2bf(v1.w) };
    *(uint4*)(xb + (size_t)row * HIDDEN + s8) = *(uint4*)o;
}

// Wt[l][j][k] = bf16(W[l][k][j])  (B^T layout, K-contiguous)
__global__ void k_cvt_w(const float* __restrict__ w, ushort* __restrict__ wt) {
    int t = blockIdx.x * blockDim.x + threadIdx.x;   // 2*512*512
    if (t >= 2 * HIDDEN * HIDDEN) return;
    int l = t >> 18;
    int rc = t & (HIDDEN * HIDDEN - 1);
    int k = rc >> 9, j = rc & 511;
    wt[(size_t)l * HIDDEN * HIDDEN + (size_t)j * HIDDEN + k] = f2bf(w[t]);
}

// agg[dst[e]] += m[src[e]] : thread = (edge, 8-col chunk), bf16 m -> f32 atomics
__global__ void k_scatter(const int* __restrict__ inputs, const int* __restrict__ A,
                          const ushort* __restrict__ m, float* __restrict__ agg) {
    bool is64 = idx_is64(inputs);
    int idx = blockIdx.x * blockDim.x + threadIdx.x;   // N_EDGES*64 threads
    int e = idx >> 6, q = (idx & 63) << 3;
    int s, d;
    if (is64) { s = A[2 * e]; d = A[2 * (N_EDGES + e)]; }
    else      { s = A[e];     d = A[N_EDGES + e]; }
    if (s < 0 || s >= N_NODES || d < 0 || d >= N_NODES) return;
    uint4 v = *(const uint4*)(m + (size_t)s * HIDDEN + q);
    const ushort* u = (const ushort*)&v;
    float* ap = agg + (size_t)d * HIDDEN + q;
    #pragma unroll
    for (int i = 0; i < 8; ++i) atomicAdd(ap + i, bf2f(u[i]));
}

// m = x @ W  (A bf16, B = Wt (B^T layout) bf16, out bf16)
__global__ __launch_bounds__(256) void k_gemm_m(const ushort* __restrict__ xb,
                                                const ushort* __restrict__ wt,
                                                ushort* __restrict__ mOut) {
    __shared__ ushort As[TM][LDP];
    __shared__ ushort Bs[TN][LDP];
    const int n0 = blockIdx.x * TM, c0 = blockIdx.y * TN;
    const int t = threadIdx.x;
    const int wave = t >> 6, lane = t & 63;
    const int wm = (wave >> 1) << 5, wn = (wave & 1) << 5;
    const int fr = lane & 15, fk = (lane >> 4) << 3;
    const int lm = t >> 2, lk = (t & 3) << 3;
    floatx4 acc[2][2] = {};

    for (int k0 = 0; k0 < HIDDEN; k0 += BK) {
        uint4 av = {0, 0, 0, 0};
        int gr = n0 + lm;
        if (gr < N_NODES) av = *(const uint4*)(xb + (size_t)gr * HIDDEN + k0 + lk);
        *(uint4*)&As[lm][lk] = av;
        *(uint4*)&Bs[lm][lk] = *(const uint4*)(wt + (size_t)(c0 + lm) * HIDDEN + k0 + lk);
        __syncthreads();
        short8 a0 = *(const short8*)&As[wm + fr][fk];
        short8 a1 = *(const short8*)&As[wm + 16 + fr][fk];
        short8 b0 = *(const short8*)&Bs[wn + fr][fk];
        short8 b1 = *(const short8*)&Bs[wn + 16 + fr][fk];
        acc[0][0] = mfma16(a0, b0, acc[0][0]);
        acc[0][1] = mfma16(a0, b1, acc[0][1]);
        acc[1][0] = mfma16(a1, b0, acc[1][0]);
        acc[1][1] = mfma16(a1, b1, acc[1][1]);
        __syncthreads();
    }
    const int er = (lane >> 4) << 2, ec = lane & 15;
    #pragma unroll
    for (int mt = 0; mt < 2; ++mt)
        #pragma unroll
        for (int nt = 0; nt < 2; ++nt)
            #pragma unroll
            for (int r = 0; r < 4; ++r) {
                int row = n0 + wm + mt * 16 + er + r;
                if (row < N_NODES)
                    mOut[(size_t)row * HIDDEN + c0 + wn + nt * 16 + ec] = f2bf(acc[mt][nt][r]);
            }
}

// Fused GRU: 4 acc sets (s_r, s_z, i_n, h_n) over 6 f32 weight tiles (staged to bf16).
__global__ __launch_bounds__(256) void k_gru(const float* __restrict__ agg,
                                             const ushort* __restrict__ xb_cur,
                                             const float* __restrict__ w_ih,
                                             const float* __restrict__ w_hh,
                                             const float* __restrict__ b_ih,
                                             const float* __restrict__ b_hh,
                                             ushort* __restrict__ xb_next) {
    __shared__ ushort Ag[TM][LDP];
    __shared__ ushort Xs[TM][LDP];
    __shared__ ushort Wsh[6][TN][LDP];   // 0..2: w_ih r,z,n ; 3..5: w_hh r,z,n
    const int n0 = blockIdx.x * TM, c0 = blockIdx.y * TN;
    const int t = threadIdx.x;
    const int wave = t >> 6, lane = t & 63;
    const int wm = (wave >> 1) << 5, wn = (wave & 1) << 5;
    const int fr = lane & 15, fk = (lane >> 4) << 3;
    const int lm = t >> 2, lk = (t & 3) << 3;
    floatx4 a_sr[2][2] = {}, a_sz[2][2] = {}, a_in[2][2] = {}, a_hn[2][2] = {};

    for (int k0 = 0; k0 < HIDDEN; k0 += BK) {
        int gr = n0 + lm;
        ushort abuf[8];
        if (gr < N_NODES) {
            const float* ap = agg + (size_t)gr * HIDDEN + k0 + lk;
            float4 v0 = *(const float4*)(ap);
            float4 v1 = *(const float4*)(ap + 4);
            abuf[0] = f2bf(v0.x); abuf[1] = f2bf(v0.y); abuf[2] = f2bf(v0.z); abuf[3] = f2bf(v0.w);
            abuf[4] = f2bf(v1.x); abuf[5] = f2bf(v1.y); abuf[6] = f2bf(v1.z); abuf[7] = f2bf(v1.w);
        } else {
            #pragma unroll
            for (int i = 0; i < 8; ++i) abuf[i] = 0;
        }
        *(uint4*)&Ag[lm][lk] = *(uint4*)abuf;
        uint4 xv = {0, 0, 0, 0};
        if (gr < N_NODES) xv = *(const uint4*)(xb_cur + (size_t)gr * HIDDEN + k0 + lk);
        *(uint4*)&Xs[lm][lk] = xv;
        #pragma unroll
        for (int g = 0; g < 6; ++g) {
            const float* wp = (g < 3 ? w_ih : w_hh) + (size_t)((g % 3) * HIDDEN + c0 + lm) * HIDDEN + k0 + lk;
            float4 u0 = *(const float4*)(wp);
            float4 u1 = *(const float4*)(wp + 4);
            ushort wb[8] = { f2bf(u0.x), f2bf(u0.y), f2bf(u0.z), f2bf(u0.w),
                             f2bf(u1.x), f2bf(u1.y), f2bf(u1.z), f2bf(u1.w) };
            *(uint4*)&Wsh[g][lm][lk] = *(uint4*)wb;
        }
        __syncthreads();
        short8 aa[2], ax[2], bw[6][2];
        aa[0] = *(const short8*)&Ag[wm + fr][fk];
        aa[1] = *(const short8*)&Ag[wm + 16 + fr][fk];
        ax[0] = *(const short8*)&Xs[wm + fr][fk];
        ax[1] = *(const short8*)&Xs[wm + 16 + fr][fk];
        #pragma unroll
        for (int g = 0; g < 6; ++g) {
            bw[g][0] = *(const short8*)&Wsh[g][wn + fr][fk];
            bw[g][1] = *(const short8*)&Wsh[g][wn + 16 + fr][fk];
        }
        #pragma unroll
        for (int mt = 0; mt < 2; ++mt)
            #pragma unroll
            for (int nt = 0; nt < 2; ++nt) {
                a_sr[mt][nt] = mfma16(aa[mt], bw[0][nt], a_sr[mt][nt]);
                a_sr[mt][nt] = mfma16(ax[mt], bw[3][nt], a_sr[mt][nt]);
                a_sz[mt][nt] = mfma16(aa[mt], bw[1][nt], a_sz[mt][nt]);
                a_sz[mt][nt] = mfma16(ax[mt], bw[4][nt], a_sz[mt][nt]);
                a_in[mt][nt] = mfma16(aa[mt], bw[2][nt], a_in[mt][nt]);
                a_hn[mt][nt] = mfma16(ax[mt], bw[5][nt], a_hn[mt][nt]);
            }
        __syncthreads();
    }
    const int er = (lane >> 4) << 2, ec = lane & 15;
    #pragma unroll
    for (int nt = 0; nt < 2; ++nt) {
        int col = c0 + wn + nt * 16 + ec;
        float bir = b_ih[col] + b_hh[col];
        float biz = b_ih[HIDDEN + col] + b_hh[HIDDEN + col];
        float bin = b_ih[2 * HIDDEN + col];
        float bhn = b_hh[2 * HIDDEN + col];
        #pragma unroll
        for (int mt = 0; mt < 2; ++mt)
            #pragma unroll
            for (int r = 0; r < 4; ++r) {
                int row = n0 + wm + mt * 16 + er + r;
                if (row >= N_NODES) continue;
                float vsr = a_sr[mt][nt][r] + bir;
                float vsz = a_sz[mt][nt][r] + biz;
                float vin = a_in[mt][nt][r] + bin;
                float vhn = a_hn[mt][nt][r] + bhn;
                float rr = 1.f / (1.f + __expf(-vsr));
                float zz = 1.f / (1.f + __expf(-vsz));
                float nn = tanhf(vin + rr * vhn);
                float h  = bf2f(xb_cur[(size_t)row * HIDDEN + col]);
                float out = (1.f - zz) * nn + zz * h;
                xb_next[(size_t)row * HIDDEN + col] = f2bf(out);
            }
    }
}

// final bf16 -> f32 into d_out
__global__ void k_cvt_out(const ushort* __restrict__ xb, float* __restrict__ out) {
    int t = blockIdx.x * blockDim.x + threadIdx.x;   // N*H/8 threads
    size_t base = (size_t)t * 8;
    if (base >= (size_t)N_NODES * HIDDEN) return;
    uint4 v = *(const uint4*)(xb + base);
    const ushort* u = (const ushort*)&v;
    float4 o0 = { bf2f(u[0]), bf2f(u[1]), bf2f(u[2]), bf2f(u[3]) };
    float4 o1 = { bf2f(u[4]), bf2f(u[5]), bf2f(u[6]), bf2f(u[7]) };
    *(float4*)(out + base) = o0;
    *(float4*)(out + base + 4) = o1;
}

extern "C" void kernel_launch(void* const* d_in, const int* in_sizes, int n_in,
                              void* d_out, int out_size, void* d_ws, size_t ws_size,
                              hipStream_t stream) {
    const int*   inputs = (const int*)d_in[0];
    const int*   A      = (const int*)d_in[1];
    const float* emb    = (const float*)d_in[2];
    const float* weight = (const float*)d_in[3];
    const float* w_ih   = (const float*)d_in[4];
    const float* w_hh   = (const float*)d_in[5];
    const float* b_ih   = (const float*)d_in[6];
    const float* b_hh   = (const float*)d_in[7];

    // ws: Wt(1MB bf16) + bufA(51.2MB bf16) + bufB(51.2MB bf16) = 103.6 MB.
    // f32 agg accumulator lives in d_out (102.4 MB); final cvt overwrites it.
    char* ws = (char*)d_ws;
    size_t off = 0;
    auto alloc = [&](size_t bytes) { void* p = ws + off; off += (bytes + 255) & ~255ull; return p; };
    ushort* Wt   = (ushort*)alloc((size_t)2 * HIDDEN * HIDDEN * sizeof(ushort));
    ushort* bufA = (ushort*)alloc((size_t)N_NODES * HIDDEN * sizeof(ushort));
    ushort* bufB = (ushort*)alloc((size_t)N_NODES * HIDDEN * sizeof(ushort));
    float*  agg  = (float*)d_out;

    k_cvt_w<<<(2 * HIDDEN * HIDDEN + 255) / 256, 256, 0, stream>>>(weight, Wt);
    k_gather<<<(N_NODES * 64 + 255) / 256, 256, 0, stream>>>(inputs, emb, bufA);

    dim3 gg((N_NODES + TM - 1) / TM, HIDDEN / TN);
    const size_t aggBytes = (size_t)N_NODES * HIDDEN * sizeof(float);

    // Layer 0: x0=bufA, m0 -> bufB, GRU -> bufB (m0 dead after scatter)
    k_gemm_m<<<gg, 256, 0, stream>>>(bufA, Wt, bufB);
    hipMemsetAsync(agg, 0, aggBytes, stream);
    k_scatter<<<(N_EDGES * 64 + 255) / 256, 256, 0, stream>>>(inputs, A, bufB, agg);
    k_gru<<<gg, 256, 0, stream>>>(agg, bufA, w_ih, w_hh, b_ih, b_hh, bufB);

    // Layer 1: x1=bufB, m1 -> bufA (x0 dead), GRU -> bufA (m1 dead after scatter)
    k_gemm_m<<<gg, 256, 0, stream>>>(bufB, Wt + (size_t)HIDDEN * HIDDEN, bufA);
    hipMemsetAsync(agg, 0, aggBytes, stream);
    k_scatter<<<(N_EDGES * 64 + 255) / 256, 256, 0, stream>>>(inputs, A, bufA, agg);
    k_gru<<<gg, 256, 0, stream>>>(agg, bufB, w_ih, w_hh, b_ih, b_hh, bufA);

    k_cvt_out<<<(N_NODES * HIDDEN / 8 + 255) / 256, 256, 0, stream>>>(bufA, (float*)d_out);
}

// Round 4
// 1271.621 us; speedup vs baseline: 5.2431x; 5.2431x over previous
//
#include <hip/hip_runtime.h>
#include <stdint.h>

#define N_NODES 50000
#define HIDDEN  512
#define N_EDGES 200000

#define TM 64
#define TN 64
#define BK 32
#define LDP 40   // padded LDS row stride in bf16 elems (80B: 16B-aligned, 2-way bank alias only)

typedef __attribute__((ext_vector_type(8))) short   short8;
typedef __attribute__((ext_vector_type(4))) float   floatx4;

__device__ inline float bf2f(ushort u) {
    union { uint32_t u; float f; } v; v.u = ((uint32_t)u) << 16; return v.f;
}
__device__ inline ushort f2bf(float f) {
    union { float f; uint32_t u; } v; v.f = f;
    uint32_t r = v.u + 0x7fffu + ((v.u >> 16) & 1u);   // round-to-nearest-even
    return (ushort)(r >> 16);
}
__device__ inline floatx4 mfma16(short8 a, short8 b, floatx4 c) {
    return __builtin_amdgcn_mfma_f32_16x16x32_bf16(a, b, c, 0, 0, 0);
}
// inputs is arange(N_NODES); if harness kept int64, the int32 view is [0,0,1,0,2,0,...]
__device__ inline bool idx_is64(const int* __restrict__ inputs) {
    return inputs[1] == 0 && inputs[2] == 1;
}

// x = bf16(emb[inputs]) : 8 f32 -> 8 bf16 per thread
__global__ void k_gather(const int* __restrict__ inputs, const float* __restrict__ emb,
                         ushort* __restrict__ xb) {
    bool is64 = idx_is64(inputs);
    int t = blockIdx.x * blockDim.x + threadIdx.x;   // N_NODES*64 threads
    int row = t >> 6, s8 = (t & 63) << 3;
    if (row >= N_NODES) return;
    int srow = is64 ? inputs[2 * row] : inputs[row];
    srow = srow < 0 ? 0 : (srow >= N_NODES ? N_NODES - 1 : srow);
    const float* src = emb + (size_t)srow * HIDDEN + s8;
    float4 v0 = *(const float4*)(src);
    float4 v1 = *(const float4*)(src + 4);
    ushort o[8] = { f2bf(v0.x), f2bf(v0.y), f2bf(v0.z), f2bf(v0.w),
                    f2bf(v1.x), f2bf(v1.y), f2bf(v1.z), f2bf(v1.w) };
    *(uint4*)(xb + (size_t)row * HIDDEN + s8) = *(uint4*)o;
}

// Wt[l][j][k] = bf16(W[l][k][j])  (B^T layout, K-contiguous)
__global__ void k_cvt_w(const float* __restrict__ w, ushort* __restrict__ wt) {
    int t = blockIdx.x * blockDim.x + threadIdx.x;   // 2*512*512
    if (t >= 2 * HIDDEN * HIDDEN) return;
    int l = t >> 18;
    int rc = t & (HIDDEN * HIDDEN - 1);
    int k = rc >> 9, j = rc & 511;
    wt[(size_t)l * HIDDEN * HIDDEN + (size_t)j * HIDDEN + k] = f2bf(w[t]);
}

// ---- counting sort of edges by dst (once per call; graph shared by both layers) ----
__global__ void k_hist(const int* __restrict__ inputs, const int* __restrict__ A,
                       int* __restrict__ count) {
    bool is64 = idx_is64(inputs);
    int e = blockIdx.x * blockDim.x + threadIdx.x;
    if (e >= N_EDGES) return;
    int d = is64 ? A[2 * (N_EDGES + e)] : A[N_EDGES + e];
    if (d < 0 || d >= N_NODES) return;
    atomicAdd(count + d, 1);
}

#define SCAN_T 1024
__global__ __launch_bounds__(SCAN_T) void k_scan(const int* __restrict__ count,
                                                 int* __restrict__ row_start,
                                                 int* __restrict__ cursor) {
    __shared__ int part[SCAN_T];
    const int t = threadIdx.x;
    const int chunk = (N_NODES + SCAN_T - 1) / SCAN_T;   // 49
    const int base = t * chunk;
    int s = 0;
    for (int i = 0; i < chunk; ++i) {
        int idx = base + i;
        if (idx < N_NODES) s += count[idx];
    }
    part[t] = s;
    __syncthreads();
    // inclusive Hillis-Steele scan of partials
    for (int off = 1; off < SCAN_T; off <<= 1) {
        int add = (t >= off) ? part[t - off] : 0;
        __syncthreads();
        part[t] += add;
        __syncthreads();
    }
    int running = (t == 0) ? 0 : part[t - 1];   // exclusive base for this chunk
    for (int i = 0; i < chunk; ++i) {
        int idx = base + i;
        if (idx < N_NODES) {
            row_start[idx] = running;
            cursor[idx] = running;
            running += count[idx];
        }
    }
    if (t == 0) row_start[N_NODES] = part[SCAN_T - 1];
}

__global__ void k_place(const int* __restrict__ inputs, const int* __restrict__ A,
                        int* __restrict__ cursor, int* __restrict__ esrc) {
    bool is64 = idx_is64(inputs);
    int e = blockIdx.x * blockDim.x + threadIdx.x;
    if (e >= N_EDGES) return;
    int s, d;
    if (is64) { s = A[2 * e]; d = A[2 * (N_EDGES + e)]; }
    else      { s = A[e];     d = A[N_EDGES + e]; }
    if (s < 0 || s >= N_NODES || d < 0 || d >= N_NODES) return;
    int pos = atomicAdd(cursor + d, 1);
    esrc[pos] = s;
}

// agg[n] = sum_{e: dst=n} m[src[e]] : one wave per node, lane owns 8 cols, f32 acc -> bf16
__global__ __launch_bounds__(256) void k_agg(const int* __restrict__ row_start,
                                             const int* __restrict__ esrc,
                                             const ushort* __restrict__ m,
                                             ushort* __restrict__ agg) {
    int node = blockIdx.x * 4 + (threadIdx.x >> 6);
    if (node >= N_NODES) return;
    int lane = threadIdx.x & 63;
    int q = lane << 3;
    int beg = row_start[node], end = row_start[node + 1];
    float acc[8] = {};
    for (int i = beg; i < end; ++i) {
        int s = esrc[i];
        uint4 v = *(const uint4*)(m + (size_t)s * HIDDEN + q);
        const ushort* u = (const ushort*)&v;
        #pragma unroll
        for (int j = 0; j < 8; ++j) acc[j] += bf2f(u[j]);
    }
    ushort o[8];
    #pragma unroll
    for (int j = 0; j < 8; ++j) o[j] = f2bf(acc[j]);
    *(uint4*)(agg + (size_t)node * HIDDEN + q) = *(uint4*)o;
}

// m = x @ W  (A bf16, B = Wt (B^T layout) bf16, out bf16)
__global__ __launch_bounds__(256) void k_gemm_m(const ushort* __restrict__ xb,
                                                const ushort* __restrict__ wt,
                                                ushort* __restrict__ mOut) {
    __shared__ ushort As[TM][LDP];
    __shared__ ushort Bs[TN][LDP];
    const int n0 = blockIdx.x * TM, c0 = blockIdx.y * TN;
    const int t = threadIdx.x;
    const int wave = t >> 6, lane = t & 63;
    const int wm = (wave >> 1) << 5, wn = (wave & 1) << 5;
    const int fr = lane & 15, fk = (lane >> 4) << 3;
    const int lm = t >> 2, lk = (t & 3) << 3;
    floatx4 acc[2][2] = {};

    for (int k0 = 0; k0 < HIDDEN; k0 += BK) {
        uint4 av = {0, 0, 0, 0};
        int gr = n0 + lm;
        if (gr < N_NODES) av = *(const uint4*)(xb + (size_t)gr * HIDDEN + k0 + lk);
        *(uint4*)&As[lm][lk] = av;
        *(uint4*)&Bs[lm][lk] = *(const uint4*)(wt + (size_t)(c0 + lm) * HIDDEN + k0 + lk);
        __syncthreads();
        short8 a0 = *(const short8*)&As[wm + fr][fk];
        short8 a1 = *(const short8*)&As[wm + 16 + fr][fk];
        short8 b0 = *(const short8*)&Bs[wn + fr][fk];
        short8 b1 = *(const short8*)&Bs[wn + 16 + fr][fk];
        acc[0][0] = mfma16(a0, b0, acc[0][0]);
        acc[0][1] = mfma16(a0, b1, acc[0][1]);
        acc[1][0] = mfma16(a1, b0, acc[1][0]);
        acc[1][1] = mfma16(a1, b1, acc[1][1]);
        __syncthreads();
    }
    const int er = (lane >> 4) << 2, ec = lane & 15;
    #pragma unroll
    for (int mt = 0; mt < 2; ++mt)
        #pragma unroll
        for (int nt = 0; nt < 2; ++nt)
            #pragma unroll
            for (int r = 0; r < 4; ++r) {
                int row = n0 + wm + mt * 16 + er + r;
                if (row < N_NODES)
                    mOut[(size_t)row * HIDDEN + c0 + wn + nt * 16 + ec] = f2bf(acc[mt][nt][r]);
            }
}

// Fused GRU: 4 acc sets (s_r, s_z, i_n, h_n) over 6 f32 weight tiles (staged to bf16).
__global__ __launch_bounds__(256) void k_gru(const ushort* __restrict__ agg,
                                             const ushort* __restrict__ xb_cur,
                                             const float* __restrict__ w_ih,
                                             const float* __restrict__ w_hh,
                                             const float* __restrict__ b_ih,
                                             const float* __restrict__ b_hh,
                                             ushort* __restrict__ xb_next) {
    __shared__ ushort Ag[TM][LDP];
    __shared__ ushort Xs[TM][LDP];
    __shared__ ushort Wsh[6][TN][LDP];   // 0..2: w_ih r,z,n ; 3..5: w_hh r,z,n
    const int n0 = blockIdx.x * TM, c0 = blockIdx.y * TN;
    const int t = threadIdx.x;
    const int wave = t >> 6, lane = t & 63;
    const int wm = (wave >> 1) << 5, wn = (wave & 1) << 5;
    const int fr = lane & 15, fk = (lane >> 4) << 3;
    const int lm = t >> 2, lk = (t & 3) << 3;
    floatx4 a_sr[2][2] = {}, a_sz[2][2] = {}, a_in[2][2] = {}, a_hn[2][2] = {};

    for (int k0 = 0; k0 < HIDDEN; k0 += BK) {
        int gr = n0 + lm;
        uint4 av = {0, 0, 0, 0}, xv = {0, 0, 0, 0};
        if (gr < N_NODES) {
            av = *(const uint4*)(agg    + (size_t)gr * HIDDEN + k0 + lk);
            xv = *(const uint4*)(xb_cur + (size_t)gr * HIDDEN + k0 + lk);
        }
        *(uint4*)&Ag[lm][lk] = av;
        *(uint4*)&Xs[lm][lk] = xv;
        #pragma unroll
        for (int g = 0; g < 6; ++g) {
            const float* wp = (g < 3 ? w_ih : w_hh) + (size_t)((g % 3) * HIDDEN + c0 + lm) * HIDDEN + k0 + lk;
            float4 u0 = *(const float4*)(wp);
            float4 u1 = *(const float4*)(wp + 4);
            ushort wb[8] = { f2bf(u0.x), f2bf(u0.y), f2bf(u0.z), f2bf(u0.w),
                             f2bf(u1.x), f2bf(u1.y), f2bf(u1.z), f2bf(u1.w) };
            *(uint4*)&Wsh[g][lm][lk] = *(uint4*)wb;
        }
        __syncthreads();
        short8 aa[2], ax[2], bw[6][2];
        aa[0] = *(const short8*)&Ag[wm + fr][fk];
        aa[1] = *(const short8*)&Ag[wm + 16 + fr][fk];
        ax[0] = *(const short8*)&Xs[wm + fr][fk];
        ax[1] = *(const short8*)&Xs[wm + 16 + fr][fk];
        #pragma unroll
        for (int g = 0; g < 6; ++g) {
            bw[g][0] = *(const short8*)&Wsh[g][wn + fr][fk];
            bw[g][1] = *(const short8*)&Wsh[g][wn + 16 + fr][fk];
        }
        #pragma unroll
        for (int mt = 0; mt < 2; ++mt)
            #pragma unroll
            for (int nt = 0; nt < 2; ++nt) {
                a_sr[mt][nt] = mfma16(aa[mt], bw[0][nt], a_sr[mt][nt]);
                a_sr[mt][nt] = mfma16(ax[mt], bw[3][nt], a_sr[mt][nt]);
                a_sz[mt][nt] = mfma16(aa[mt], bw[1][nt], a_sz[mt][nt]);
                a_sz[mt][nt] = mfma16(ax[mt], bw[4][nt], a_sz[mt][nt]);
                a_in[mt][nt] = mfma16(aa[mt], bw[2][nt], a_in[mt][nt]);
                a_hn[mt][nt] = mfma16(ax[mt], bw[5][nt], a_hn[mt][nt]);
            }
        __syncthreads();
    }
    const int er = (lane >> 4) << 2, ec = lane & 15;
    #pragma unroll
    for (int nt = 0; nt < 2; ++nt) {
        int col = c0 + wn + nt * 16 + ec;
        float bir = b_ih[col] + b_hh[col];
        float biz = b_ih[HIDDEN + col] + b_hh[HIDDEN + col];
        float bin = b_ih[2 * HIDDEN + col];
        float bhn = b_hh[2 * HIDDEN + col];
        #pragma unroll
        for (int mt = 0; mt < 2; ++mt)
            #pragma unroll
            for (int r = 0; r < 4; ++r) {
                int row = n0 + wm + mt * 16 + er + r;
                if (row >= N_NODES) continue;
                float vsr = a_sr[mt][nt][r] + bir;
                float vsz = a_sz[mt][nt][r] + biz;
                float vin = a_in[mt][nt][r] + bin;
                float vhn = a_hn[mt][nt][r] + bhn;
                float rr = 1.f / (1.f + __expf(-vsr));
                float zz = 1.f / (1.f + __expf(-vsz));
                float nn = tanhf(vin + rr * vhn);
                float h  = bf2f(xb_cur[(size_t)row * HIDDEN + col]);
                float out = (1.f - zz) * nn + zz * h;
                xb_next[(size_t)row * HIDDEN + col] = f2bf(out);
            }
    }
}

// final bf16 -> f32 into d_out
__global__ void k_cvt_out(const ushort* __restrict__ xb, float* __restrict__ out) {
    int t = blockIdx.x * blockDim.x + threadIdx.x;   // N*H/8 threads
    size_t base = (size_t)t * 8;
    if (base >= (size_t)N_NODES * HIDDEN) return;
    uint4 v = *(const uint4*)(xb + base);
    const ushort* u = (const ushort*)&v;
    float4 o0 = { bf2f(u[0]), bf2f(u[1]), bf2f(u[2]), bf2f(u[3]) };
    float4 o1 = { bf2f(u[4]), bf2f(u[5]), bf2f(u[6]), bf2f(u[7]) };
    *(float4*)(out + base) = o0;
    *(float4*)(out + base + 4) = o1;
}

extern "C" void kernel_launch(void* const* d_in, const int* in_sizes, int n_in,
                              void* d_out, int out_size, void* d_ws, size_t ws_size,
                              hipStream_t stream) {
    const int*   inputs = (const int*)d_in[0];
    const int*   A      = (const int*)d_in[1];
    const float* emb    = (const float*)d_in[2];
    const float* weight = (const float*)d_in[3];
    const float* w_ih   = (const float*)d_in[4];
    const float* w_hh   = (const float*)d_in[5];
    const float* b_ih   = (const float*)d_in[6];
    const float* b_hh   = (const float*)d_in[7];

    // ws: Wt(1MB) + bufA(51.2MB) + bufB(51.2MB) + sort arrays (~1.4MB) = ~104.8 MB.
    // bf16 agg (51.2MB) lives in d_out (102.4MB); final cvt overwrites it.
    char* ws = (char*)d_ws;
    size_t off = 0;
    auto alloc = [&](size_t bytes) { void* p = ws + off; off += (bytes + 255) & ~255ull; return p; };
    ushort* Wt        = (ushort*)alloc((size_t)2 * HIDDEN * HIDDEN * sizeof(ushort));
    ushort* bufA      = (ushort*)alloc((size_t)N_NODES * HIDDEN * sizeof(ushort));
    ushort* bufB      = (ushort*)alloc((size_t)N_NODES * HIDDEN * sizeof(ushort));
    int*    count     = (int*)alloc((size_t)N_NODES * sizeof(int));
    int*    row_start = (int*)alloc((size_t)(N_NODES + 1) * sizeof(int));
    int*    cursor    = (int*)alloc((size_t)N_NODES * sizeof(int));
    int*    esrc      = (int*)alloc((size_t)N_EDGES * sizeof(int));
    ushort* agg       = (ushort*)d_out;

    k_cvt_w<<<(2 * HIDDEN * HIDDEN + 255) / 256, 256, 0, stream>>>(weight, Wt);
    k_gather<<<(N_NODES * 64 + 255) / 256, 256, 0, stream>>>(inputs, emb, bufA);

    // Edge sort by dst (shared by both layers)
    hipMemsetAsync(count, 0, (size_t)N_NODES * sizeof(int), stream);
    k_hist<<<(N_EDGES + 255) / 256, 256, 0, stream>>>(inputs, A, count);
    k_scan<<<1, SCAN_T, 0, stream>>>(count, row_start, cursor);
    k_place<<<(N_EDGES + 255) / 256, 256, 0, stream>>>(inputs, A, cursor, esrc);

    dim3 gg((N_NODES + TM - 1) / TM, HIDDEN / TN);
    dim3 ga((N_NODES + 3) / 4);

    // Layer 0: x0=bufA, m0 -> bufB, agg -> d_out, GRU -> bufB (m0 dead after agg)
    k_gemm_m<<<gg, 256, 0, stream>>>(bufA, Wt, bufB);
    k_agg<<<ga, 256, 0, stream>>>(row_start, esrc, bufB, agg);
    k_gru<<<gg, 256, 0, stream>>>(agg, bufA, w_ih, w_hh, b_ih, b_hh, bufB);

    // Layer 1: x1=bufB, m1 -> bufA (x0 dead), agg -> d_out, GRU -> bufA
    k_gemm_m<<<gg, 256, 0, stream>>>(bufB, Wt + (size_t)HIDDEN * HIDDEN, bufA);
    k_agg<<<ga, 256, 0, stream>>>(row_start, esrc, bufA, agg);
    k_gru<<<gg, 256, 0, stream>>>(agg, bufB, w_ih, w_hh, b_ih, b_hh, bufA);

    k_cvt_out<<<(N_NODES * HIDDEN / 8 + 255) / 256, 256, 0, stream>>>(bufA, (float*)d_out);
}